// Round 24
// baseline (61.881 us; speedup 1.0000x reference)
//
#include <hip/hip_runtime.h>
#include <hip/hip_bf16.h>
#include <hip/hip_fp16.h>
#include <stdint.h>

// Problem constants
#define BATCH 256
#define NPOS 49
#define CCH 128
#define KWIN 7
#define HEADS 4
#define K2 49
#define HD 32
#define MROWS (BATCH * NPOS)         // 12544
#define QSCALE 0.17677669529663687f  // 32^-0.5

using short8 = __attribute__((ext_vector_type(8))) short;
using floatx4 = __attribute__((ext_vector_type(4))) float;

static __device__ inline short f2bf(float x) {
  uint32_t u = __float_as_uint(x);
  uint32_t r = (u + 0x7fffu + ((u >> 16) & 1u)) >> 16;
  return (short)r;
}
static __device__ inline float bf2f(short s) {
  return __uint_as_float(((uint32_t)(unsigned short)s) << 16);
}

// ---------------------------------------------------------------------------
// GEMM 0 (r15): x @ [w_qkv;w_off]^T -> qkv_bf (bf16, q pre-scaled) + off_h.
// ---------------------------------------------------------------------------
__global__ __launch_bounds__(256) void dwa_gemm0(
    const float* __restrict__ x, const float* __restrict__ w_qkv,
    const float* __restrict__ w_off, const float* __restrict__ b_qkv,
    const float* __restrict__ b_off, short* __restrict__ qkv_bf,
    __half* __restrict__ off_h) {
  __shared__ short Abs[64][128];
  __shared__ short Bbs[64][128];
  const int tid = threadIdx.x;
  const int m0 = blockIdx.x * 64;

#pragma unroll
  for (int p = 0; p < 4; ++p) {
    int c = tid + p * 256;
    int row = c >> 4;
    int slot = c & 15;
    const float* src = x + (size_t)(m0 + row) * 128 + slot * 8;
    float4 f0 = *(const float4*)(src);
    float4 f1 = *(const float4*)(src + 4);
    short8 pk;
    pk[0] = f2bf(f0.x); pk[1] = f2bf(f0.y); pk[2] = f2bf(f0.z); pk[3] = f2bf(f0.w);
    pk[4] = f2bf(f1.x); pk[5] = f2bf(f1.y); pk[6] = f2bf(f1.z); pk[7] = f2bf(f1.w);
    *(short8*)&Abs[row][(slot ^ (row & 7)) * 8] = pk;
  }

  const int lane = tid & 63;
  const int wv = tid >> 6;
  const int wrow = (wv >> 1) * 32;
  const int wcol = (wv & 1) * 32;
  const int lr = lane & 15;
  const int lg = lane >> 4;

#pragma unroll
  for (int t = 0; t < 3; ++t) {
    const int ntile = blockIdx.y + 5 * t;
    if (ntile >= 13) break;
    const int n0 = ntile * 64;
#pragma unroll
    for (int p = 0; p < 4; ++p) {
      int c = tid + p * 256;
      int row = c >> 4;
      int slot = c & 15;
      int colg = n0 + row;
      float4 f0 = make_float4(0.f, 0.f, 0.f, 0.f), f1 = f0;
      if (colg < 384) {
        const float* src = w_qkv + (size_t)colg * 128 + slot * 8;
        f0 = *(const float4*)(src);
        f1 = *(const float4*)(src + 4);
      } else if (colg < 776) {
        const float* src = w_off + (size_t)(colg - 384) * 128 + slot * 8;
        f0 = *(const float4*)(src);
        f1 = *(const float4*)(src + 4);
      }
      short8 pk;
      pk[0] = f2bf(f0.x); pk[1] = f2bf(f0.y); pk[2] = f2bf(f0.z); pk[3] = f2bf(f0.w);
      pk[4] = f2bf(f1.x); pk[5] = f2bf(f1.y); pk[6] = f2bf(f1.z); pk[7] = f2bf(f1.w);
      *(short8*)&Bbs[row][(slot ^ (row & 7)) * 8] = pk;
    }
    __syncthreads();

    floatx4 acc[2][2];
#pragma unroll
    for (int i = 0; i < 2; ++i)
#pragma unroll
      for (int j = 0; j < 2; ++j) acc[i][j] = {0.f, 0.f, 0.f, 0.f};
#pragma unroll
    for (int ks = 0; ks < 4; ++ks) {
      short8 af[2], bf[2];
#pragma unroll
      for (int i = 0; i < 2; ++i) {
        int r = wrow + i * 16 + lr;
        int slot = (ks * 4 + lg) ^ (r & 7);
        af[i] = *(const short8*)&Abs[r][slot * 8];
      }
#pragma unroll
      for (int j = 0; j < 2; ++j) {
        int r = wcol + j * 16 + lr;
        int slot = (ks * 4 + lg) ^ (r & 7);
        bf[j] = *(const short8*)&Bbs[r][slot * 8];
      }
#pragma unroll
      for (int i = 0; i < 2; ++i)
#pragma unroll
        for (int j = 0; j < 2; ++j)
          acc[i][j] = __builtin_amdgcn_mfma_f32_16x16x32_bf16(af[i], bf[j],
                                                              acc[i][j], 0, 0, 0);
    }
#pragma unroll
    for (int i = 0; i < 2; ++i) {
#pragma unroll
      for (int reg = 0; reg < 4; ++reg) {
        int grow = m0 + wrow + i * 16 + lg * 4 + reg;
#pragma unroll
        for (int j = 0; j < 2; ++j) {
          int gcol = n0 + wcol + j * 16 + lr;
          float v = acc[i][j][reg];
          if (gcol < 384) {
            float sc = (gcol < 128) ? QSCALE : 1.0f;
            qkv_bf[(size_t)grow * 384 + gcol] = f2bf((v + b_qkv[gcol]) * sc);
          } else if (gcol < 776) {
            off_h[(size_t)grow * 392 + (gcol - 384)] =
                __float2half(v + b_off[gcol - 384]);
          }
        }
      }
    }
    __syncthreads();
  }
}

// ---------------------------------------------------------------------------
// Deformable window attention (r23 base). r24 delta: 3-tile reduce.
//  - scr shrinks to [48][64] (cells 0..47). Raw neighbor cells > 48 are only
//    reachable via clamping (weights exactly 0) -> dropped, not stored.
//  - cell-48 contributions stay in registers; summed via 6-step shfl_xor
//    (fp32); lane 0 writes {c48,0,0,0} at m=48; lanes 16/32/48 zero m=52..63.
//  - reduce: 3 MFMA tiles (rows 0..47) instead of 4 -> 6 b128 + 6 MFMA/row.
//  - scatter + re-zero stores predicated on cell < 48 (border rows store
//    fewer); trash row and its zeroing deleted.
// One block per (b,h,half); 2048 x 256 threads; LDS ~39.6 KB -> 4 blocks/CU.
// ---------------------------------------------------------------------------
__global__ __launch_bounds__(256, 4) void dwa_attn(
    const short* __restrict__ qkv_bf, const __half* __restrict__ off_h,
    const float* __restrict__ rpb, short* __restrict__ attn_bf,
    float* __restrict__ rs_buf) {
  __shared__ __align__(16) short scr_all[4 * 3072];  // per-wave [48][64] bf16
  __shared__ __align__(16) short region1[3840];   // qbs(1280)+kbs(2560) / A2b
  __shared__ __align__(16) __half S0h[1356];      // [26][52] fp16 + pad
  __shared__ __align__(16) short vbT[32 * 72];    // bf16 v^T [d][m]

  short* qbs = region1;          // [32][40] bf16
  short* kbs = region1 + 1280;   // [64][40] bf16
  short* A2b = region1;          // [32][72] bf16 (aliases qbs/kbs after P2)

  const int bid = blockIdx.x;
  const int swz = (bid & 7) * 256 + (bid >> 3);
  const int b = swz >> 3;
  const int sub = swz & 7;
  const int h = sub >> 1;
  const int half = sub & 1;
  const int bn0 = half * 25;
  const int rcnt = half ? 24 : 25;

  const int tid = threadIdx.x;
  const int lane = tid & 63;
  const int wv = tid >> 6;
  const int lr = lane & 15;
  const int lg = lane >> 4;
  short* scr = scr_all + wv * 3072;  // this wave's [48][64] bf16 scratch

  // per-lane k2 constants (lane = k2)
  const int kk2 = (lane < 49) ? lane : 48;
  const int ky = kk2 / 7;
  const int kx = kk2 - ky * 7;
  const float bias_r = rpb[h * 169 + (ky + 3) * 13 + (kx + 3)];

  // ---- prefetch offsets for my wave's rows (<=7) ----
  const __half* offp = off_h + (size_t)(b * 49) * 392 + h * 98;
  float2 offr[7];
#pragma unroll
  for (int i = 0; i < 7; ++i) {
    int nl = wv + 4 * i;
    if (nl < rcnt && lane < 49) {
      __half2 o2 =
          *(const __half2*)(offp + (size_t)(bn0 + nl) * 392 + lane * 2);
      offr[i] = __half22float2(o2);
    } else {
      offr[i] = make_float2(0.f, 0.f);
    }
  }

  // ---- P1 stage (pure copies) + full scr zero (once) ----
  {
    short8 zz = {0, 0, 0, 0, 0, 0, 0, 0};
    {
      int r = tid >> 2, c4 = tid & 3;
      short8 pk = zz;
      if (r < 49)
        pk = *(const short8*)(qkv_bf + (size_t)(b * 49 + r) * 384 + 128 +
                              h * 32 + c4 * 8);
      *(short8*)&kbs[r * 40 + c4 * 8] = pk;
    }
    if (tid < 128) {
      int r = tid >> 2, c4 = tid & 3;
      short8 pk = zz;
      if (r < rcnt)
        pk = *(const short8*)(qkv_bf + (size_t)(b * 49 + bn0 + r) * 384 +
                              h * 32 + c4 * 8);
      *(short8*)&qbs[r * 40 + c4 * 8] = pk;
    }
    const short* vbase = qkv_bf + (size_t)(b * 49) * 384 + 256 + h * 32;
#pragma unroll
    for (int it = 0; it < 7; ++it) {
      int i = tid + it * 256;
      if (i < 1568) {
        int n = i >> 5;
        int d = i & 31;
        vbT[d * 72 + n] = vbase[(size_t)n * 384 + d];
      }
    }
    for (int i = tid; i < 480; i += 256) {  // zero vbT cols 49..63, all d
      int d = i / 15;
      int j = i - d * 15;
      vbT[d * 72 + 49 + j] = 0;
    }
    if (tid < 16) S0h[25 * 52 + tid] = __float2half(0.f);
    // zero this wave's FULL scr (48 rows x 64 = 384 chunks of 8)
    for (int c = lane; c < 384; c += 64) *(short8*)&scr[c * 8] = zz;
  }
  __syncthreads();  // B1

  // ---- P2: S0h[n][m] = k_m . q_n via mfma(A=k, B=q); fp16 b64 writes ----
  {
    const int mt = wv;
    short8 af = *(const short8*)&kbs[(mt * 16 + lr) * 40 + lg * 8];
    floatx4 z = {0.f, 0.f, 0.f, 0.f};
#pragma unroll
    for (int nt = 0; nt < 2; ++nt) {
      short8 bf = *(const short8*)&qbs[(nt * 16 + lr) * 40 + lg * 8];
      floatx4 c = __builtin_amdgcn_mfma_f32_16x16x32_bf16(af, bf, z, 0, 0, 0);
      int n = nt * 16 + lr;
      int mbase = mt * 16 + lg * 4;
      if (n < 26 && mbase < 52) {  // both guards required (row pitch 52)
        short4 pk;
        pk.x = (short)__half_as_ushort(__float2half(c[0]));
        pk.y = (short)__half_as_ushort(__float2half(c[1]));
        pk.z = (short)__half_as_ushort(__float2half(c[2]));
        pk.w = (short)__half_as_ushort(__float2half(c[3]));
        *(short4*)&S0h[n * 52 + mbase] = pk;
      }
    }
  }
  __syncthreads();  // B2 (q/k region dead; A2b region writable per-wave)

  // ---- P3: per-wave row loop -- scores + predicated scatter + 3-tile
  //      MFMA reduce + shfl cell-48 ----
  {
    short8 bones;
#pragma unroll
    for (int u = 0; u < 8; ++u) bones[u] = (lr == 0) ? (short)0x3F80 : (short)0;
    const int lchunk = lane >> 3;
    const int lsub = lane & 7;
    const short4 zz4 = {0, 0, 0, 0};

#pragma unroll
    for (int i = 0; i < 7; ++i) {
      const int nl = wv + 4 * i;
      if (nl >= rcnt) break;
      int so0 = -1, so1 = -1, so2 = -1, so3 = -1;
      float c48 = 0.f;
      if (lane < 49) {
        const int gn = bn0 + nl;
        const int iy = (int)((unsigned)gn / 7u);
        const int ix = gn - iy * 7;
        float py = fminf(fmaxf((float)(iy + ky - 3) + offr[i].x, 0.f), 6.f);
        float px = fminf(fmaxf((float)(ix + kx - 3) + offr[i].y, 0.f), 6.f);
        float y0f = floorf(py), x0f = floorf(px);
        float wy = py - y0f, wx = px - x0f;
        int y0 = (int)y0f, x0 = (int)x0f;
        int c00 = y0 * 7 + x0;       // 0..48
        int c01 = c00 + 1;           // raw; >48 only when clamped (w==0)
        int c10 = c00 + 7;
        int c11 = c00 + 8;
        int sbase = nl * 52 + c00;
        float s00 = __half2float(S0h[sbase]);
        float s01 = __half2float(S0h[sbase + 1]);
        float s10 = __half2float(S0h[sbase + 7]);
        float s11 = __half2float(S0h[sbase + 8]);
        float w00 = (1.f - wy) * (1.f - wx);
        float w01 = (1.f - wy) * wx;
        float w10 = wy * (1.f - wx);
        float w11 = wy * wx;
        float s = w00 * s00 + w01 * s01 + w10 * s10 + w11 * s11 + bias_r;
        float pe = __expf(s);
        float v0 = pe * w00, v1 = pe * w01, v2 = pe * w10, v3 = pe * w11;
        if (c00 < 48) {
          so0 = c00 * 64 + ((lchunk ^ (c00 & 7)) * 8) + lsub;
          scr[so0] = f2bf(v0);
        } else {  // c00 == 48
          c48 += v0;
        }
        if (c01 < 48) {
          so1 = c01 * 64 + ((lchunk ^ (c01 & 7)) * 8) + lsub;
          scr[so1] = f2bf(v1);
        } else if (c01 == 48) {
          c48 += v1;
        }  // c01 > 48: clamped, v1 == 0, drop
        if (c10 < 48) {
          so2 = c10 * 64 + ((lchunk ^ (c10 & 7)) * 8) + lsub;
          scr[so2] = f2bf(v2);
        } else if (c10 == 48) {
          c48 += v2;
        }
        if (c11 < 48) {
          so3 = c11 * 64 + ((lchunk ^ (c11 & 7)) * 8) + lsub;
          scr[so3] = f2bf(v3);
        } else if (c11 == 48) {
          c48 += v3;
        }
      }
      // cell-48 wave reduction (fp32); lanes >= 49 contribute 0
#pragma unroll
      for (int d = 32; d; d >>= 1) c48 += __shfl_xor(c48, d);
      // reduce: A2row[m 0..47] via ones-B MFMA over 3 tiles
      __builtin_amdgcn_s_setprio(1);
#pragma unroll
      for (int tile = 0; tile < 3; ++tile) {
        floatx4 cacc = {0.f, 0.f, 0.f, 0.f};
#pragma unroll
        for (int ks = 0; ks < 2; ++ks) {
          int row = tile * 16 + lr;
          int chunk = ks * 4 + lg;
          short8 af =
              *(const short8*)&scr[row * 64 + ((chunk ^ (row & 7)) * 8)];
          cacc = __builtin_amdgcn_mfma_f32_16x16x32_bf16(af, bones, cacc,
                                                         0, 0, 0);
        }
        if ((lane & 15) == 0) {
          int mb = tile * 16 + (lane >> 4) * 4;
#pragma unroll
          for (int reg = 0; reg < 4; ++reg) {
            A2b[nl * 72 + mb + reg] = f2bf(cacc[reg]);  // m <= 47
          }
        }
      }
      __builtin_amdgcn_s_setprio(0);
      // tail m = 48..63: lane 0 writes {c48,0,0,0}; 16/32/48 write zeros
      if (lane == 0) {
        short4 t = zz4;
        t.x = f2bf(c48);
        *(short4*)&A2b[nl * 72 + 48] = t;
      } else if (lane == 16) {
        *(short4*)&A2b[nl * 72 + 52] = zz4;
      } else if (lane == 32) {
        *(short4*)&A2b[nl * 72 + 56] = zz4;
      } else if (lane == 48) {
        *(short4*)&A2b[nl * 72 + 60] = zz4;
      }
      // re-zero stored slots (predicated to mirror the scatter)
      if (so0 >= 0) scr[so0] = 0;
      if (so1 >= 0) scr[so1] = 0;
      if (so2 >= 0) scr[so2] = 0;
      if (so3 >= 0) scr[so3] = 0;
    }
  }
  __syncthreads();  // B3

  // ---- P5: out (bf16, unnormalized) + rowsum via MFMA ----
  {
    const int nt = wv & 1;
    const int dt = wv >> 1;
    floatx4 acc = {0.f, 0.f, 0.f, 0.f};
    floatx4 accS = {0.f, 0.f, 0.f, 0.f};
    short8 bones;
#pragma unroll
    for (int u = 0; u < 8; ++u) bones[u] = (lr == 0) ? (short)0x3F80 : (short)0;
#pragma unroll
    for (int ks = 0; ks < 2; ++ks) {
      short8 af = *(const short8*)&A2b[(nt * 16 + lr) * 72 + ks * 32 + lg * 8];
      short8 bf = *(const short8*)&vbT[(dt * 16 + lr) * 72 + ks * 32 + lg * 8];
      acc = __builtin_amdgcn_mfma_f32_16x16x32_bf16(af, bf, acc, 0, 0, 0);
      if (dt == 0)
        accS = __builtin_amdgcn_mfma_f32_16x16x32_bf16(af, bones, accS, 0, 0, 0);
    }
    const int d = dt * 16 + lr;
#pragma unroll
    for (int reg = 0; reg < 4; ++reg) {
      int n = nt * 16 + lg * 4 + reg;
      if (n < rcnt) {
        int grow = b * 49 + bn0 + n;
        attn_bf[(size_t)grow * 128 + h * 32 + d] = f2bf(acc[reg]);
        if (dt == 0 && lr == 0) rs_buf[(size_t)grow * 4 + h] = accS[reg];
      }
    }
  }
}

// ---------------------------------------------------------------------------
// Proj GEMM: out = diag(1/rs per head) * attn_bf @ w_proj^T + b_proj
// ---------------------------------------------------------------------------
__global__ __launch_bounds__(256) void dwa_proj(
    const short* __restrict__ A, const float* __restrict__ W0,
    const float* __restrict__ bias0, float* __restrict__ out0,
    const float* __restrict__ rs) {
  __shared__ short Abs[64][128];
  __shared__ short Bbs[64][128];
  const int tid = threadIdx.x;
  const int m0 = blockIdx.x * 64;
  const int n0 = blockIdx.y * 64;

#pragma unroll
  for (int p = 0; p < 4; ++p) {
    int c = tid + p * 256;
    int row = c >> 4;
    int slot = c & 15;
    short8 v = *(const short8*)(A + (size_t)(m0 + row) * 128 + slot * 8);
    float irs = 1.0f / rs[(size_t)(m0 + row) * 4 + (slot >> 2)];
    short8 pk;
#pragma unroll
    for (int u = 0; u < 8; ++u) pk[u] = f2bf(bf2f(v[u]) * irs);
    *(short8*)&Abs[row][(slot ^ (row & 7)) * 8] = pk;
  }
#pragma unroll
  for (int p = 0; p < 4; ++p) {
    int c = tid + p * 256;
    int row = c >> 4;
    int slot = c & 15;
    const float* src = W0 + (size_t)(n0 + row) * 128 + slot * 8;
    float4 f0 = *(const float4*)(src);
    float4 f1 = *(const float4*)(src + 4);
    short8 pk;
    pk[0] = f2bf(f0.x); pk[1] = f2bf(f0.y); pk[2] = f2bf(f0.z); pk[3] = f2bf(f0.w);
    pk[4] = f2bf(f1.x); pk[5] = f2bf(f1.y); pk[6] = f2bf(f1.z); pk[7] = f2bf(f1.w);
    *(short8*)&Bbs[row][(slot ^ (row & 7)) * 8] = pk;
  }
  __syncthreads();

  const int lane = tid & 63;
  const int wv = tid >> 6;
  const int wrow = (wv >> 1) * 32;
  const int wcol = (wv & 1) * 32;
  const int lr = lane & 15;
  const int lg = lane >> 4;

  floatx4 acc[2][2];
#pragma unroll
  for (int i = 0; i < 2; ++i)
#pragma unroll
    for (int j = 0; j < 2; ++j) acc[i][j] = {0.f, 0.f, 0.f, 0.f};

#pragma unroll
  for (int ks = 0; ks < 4; ++ks) {
    short8 af[2], bf[2];
#pragma unroll
    for (int i = 0; i < 2; ++i) {
      int r = wrow + i * 16 + lr;
      int slot = (ks * 4 + lg) ^ (r & 7);
      af[i] = *(const short8*)&Abs[r][slot * 8];
    }
#pragma unroll
    for (int j = 0; j < 2; ++j) {
      int r = wcol + j * 16 + lr;
      int slot = (ks * 4 + lg) ^ (r & 7);
      bf[j] = *(const short8*)&Bbs[r][slot * 8];
    }
#pragma unroll
    for (int i = 0; i < 2; ++i)
#pragma unroll
      for (int j = 0; j < 2; ++j)
        acc[i][j] = __builtin_amdgcn_mfma_f32_16x16x32_bf16(af[i], bf[j],
                                                            acc[i][j], 0, 0, 0);
  }

#pragma unroll
  for (int i = 0; i < 2; ++i) {
#pragma unroll
    for (int reg = 0; reg < 4; ++reg) {
      int grow = m0 + wrow + i * 16 + lg * 4 + reg;
#pragma unroll
      for (int j = 0; j < 2; ++j) {
        int gcol = n0 + wcol + j * 16 + lr;
        out0[(size_t)grow * 128 + gcol] = acc[i][j][reg] + bias0[gcol];
      }
    }
  }
}

// ---------------------------------------------------------------------------
extern "C" void kernel_launch(void* const* d_in, const int* in_sizes, int n_in,
                              void* d_out, int out_size, void* d_ws,
                              size_t ws_size, hipStream_t stream) {
  const float* x = (const float*)d_in[0];
  const float* w_qkv = (const float*)d_in[1];
  const float* b_qkv = (const float*)d_in[2];
  const float* w_off = (const float*)d_in[3];
  const float* b_off = (const float*)d_in[4];
  const float* rpb = (const float*)d_in[5];
  const float* w_proj = (const float*)d_in[6];
  const float* b_proj = (const float*)d_in[7];
  float* out = (float*)d_out;

  char* ws = (char*)d_ws;
  short* qkv_bf = (short*)ws;                               // 9,633,792 B
  __half* off_h = (__half*)(ws + 9633792);                  // 9,834,496 B
  short* attn_bf = (short*)(ws + 19468288);                 // 3,211,264 B
  float* rs_buf = (float*)(ws + 22679552);                  // 200,704 B

  dwa_gemm0<<<dim3(196, 5), 256, 0, stream>>>(x, w_qkv, w_off, b_qkv, b_off,
                                              qkv_bf, off_h);
  dwa_attn<<<2048, 256, 0, stream>>>(qkv_bf, off_h, rpb, attn_bf, rs_buf);
  dwa_proj<<<dim3(196, 2), 256, 0, stream>>>(attn_bf, w_proj, b_proj, out,
                                             rs_buf);
}

// Round 25
// 56.552 us; speedup vs baseline: 1.0942x; 1.0942x over previous
//
#include <hip/hip_runtime.h>
#include <hip/hip_bf16.h>
#include <hip/hip_fp16.h>
#include <stdint.h>

// Problem constants
#define BATCH 256
#define NPOS 49
#define CCH 128
#define KWIN 7
#define HEADS 4
#define K2 49
#define HD 32
#define MROWS (BATCH * NPOS)         // 12544
#define QSCALE 0.17677669529663687f  // 32^-0.5

using short8 = __attribute__((ext_vector_type(8))) short;
using floatx4 = __attribute__((ext_vector_type(4))) float;

static __device__ inline short f2bf(float x) {
  uint32_t u = __float_as_uint(x);
  uint32_t r = (u + 0x7fffu + ((u >> 16) & 1u)) >> 16;
  return (short)r;
}
static __device__ inline float bf2f(short s) {
  return __uint_as_float(((uint32_t)(unsigned short)s) << 16);
}

// ---------------------------------------------------------------------------
// GEMM 0: x @ [w_qkv;w_off]^T -> qkv_bf (bf16, q pre-scaled) + off_h (fp16).
// ---------------------------------------------------------------------------
__global__ __launch_bounds__(256) void dwa_gemm0(
    const float* __restrict__ x, const float* __restrict__ w_qkv,
    const float* __restrict__ w_off, const float* __restrict__ b_qkv,
    const float* __restrict__ b_off, short* __restrict__ qkv_bf,
    __half* __restrict__ off_h) {
  __shared__ short Abs[64][128];
  __shared__ short Bbs[64][128];
  const int tid = threadIdx.x;
  const int m0 = blockIdx.x * 64;

#pragma unroll
  for (int p = 0; p < 4; ++p) {
    int c = tid + p * 256;
    int row = c >> 4;
    int slot = c & 15;
    const float* src = x + (size_t)(m0 + row) * 128 + slot * 8;
    float4 f0 = *(const float4*)(src);
    float4 f1 = *(const float4*)(src + 4);
    short8 pk;
    pk[0] = f2bf(f0.x); pk[1] = f2bf(f0.y); pk[2] = f2bf(f0.z); pk[3] = f2bf(f0.w);
    pk[4] = f2bf(f1.x); pk[5] = f2bf(f1.y); pk[6] = f2bf(f1.z); pk[7] = f2bf(f1.w);
    *(short8*)&Abs[row][(slot ^ (row & 7)) * 8] = pk;
  }

  const int lane = tid & 63;
  const int wv = tid >> 6;
  const int wrow = (wv >> 1) * 32;
  const int wcol = (wv & 1) * 32;
  const int lr = lane & 15;
  const int lg = lane >> 4;

#pragma unroll
  for (int t = 0; t < 3; ++t) {
    const int ntile = blockIdx.y + 5 * t;
    if (ntile >= 13) break;
    const int n0 = ntile * 64;
#pragma unroll
    for (int p = 0; p < 4; ++p) {
      int c = tid + p * 256;
      int row = c >> 4;
      int slot = c & 15;
      int colg = n0 + row;
      float4 f0 = make_float4(0.f, 0.f, 0.f, 0.f), f1 = f0;
      if (colg < 384) {
        const float* src = w_qkv + (size_t)colg * 128 + slot * 8;
        f0 = *(const float4*)(src);
        f1 = *(const float4*)(src + 4);
      } else if (colg < 776) {
        const float* src = w_off + (size_t)(colg - 384) * 128 + slot * 8;
        f0 = *(const float4*)(src);
        f1 = *(const float4*)(src + 4);
      }
      short8 pk;
      pk[0] = f2bf(f0.x); pk[1] = f2bf(f0.y); pk[2] = f2bf(f0.z); pk[3] = f2bf(f0.w);
      pk[4] = f2bf(f1.x); pk[5] = f2bf(f1.y); pk[6] = f2bf(f1.z); pk[7] = f2bf(f1.w);
      *(short8*)&Bbs[row][(slot ^ (row & 7)) * 8] = pk;
    }
    __syncthreads();

    floatx4 acc[2][2];
#pragma unroll
    for (int i = 0; i < 2; ++i)
#pragma unroll
      for (int j = 0; j < 2; ++j) acc[i][j] = {0.f, 0.f, 0.f, 0.f};
#pragma unroll
    for (int ks = 0; ks < 4; ++ks) {
      short8 af[2], bf[2];
#pragma unroll
      for (int i = 0; i < 2; ++i) {
        int r = wrow + i * 16 + lr;
        int slot = (ks * 4 + lg) ^ (r & 7);
        af[i] = *(const short8*)&Abs[r][slot * 8];
      }
#pragma unroll
      for (int j = 0; j < 2; ++j) {
        int r = wcol + j * 16 + lr;
        int slot = (ks * 4 + lg) ^ (r & 7);
        bf[j] = *(const short8*)&Bbs[r][slot * 8];
      }
#pragma unroll
      for (int i = 0; i < 2; ++i)
#pragma unroll
        for (int j = 0; j < 2; ++j)
          acc[i][j] = __builtin_amdgcn_mfma_f32_16x16x32_bf16(af[i], bf[j],
                                                              acc[i][j], 0, 0, 0);
    }
#pragma unroll
    for (int i = 0; i < 2; ++i) {
#pragma unroll
      for (int reg = 0; reg < 4; ++reg) {
        int grow = m0 + wrow + i * 16 + lg * 4 + reg;
#pragma unroll
        for (int j = 0; j < 2; ++j) {
          int gcol = n0 + wcol + j * 16 + lr;
          float v = acc[i][j][reg];
          if (gcol < 384) {
            float sc = (gcol < 128) ? QSCALE : 1.0f;
            qkv_bf[(size_t)grow * 384 + gcol] = f2bf((v + b_qkv[gcol]) * sc);
          } else if (gcol < 776) {
            off_h[(size_t)grow * 392 + (gcol - 384)] =
                __float2half(v + b_off[gcol - 384]);
          }
        }
      }
    }
    __syncthreads();
  }
}

// ---------------------------------------------------------------------------
// Deformable window attention (final: r23 structure, best measured 56.6us).
// One block per (b,h,half); 2048 x 256 threads; LDS 40.9 KB -> 4 blocks/CU.
// Atomic-free scatter: wave owns rows n = wv+4i; per-lane distinct scratch
// cells (clamped duplicates -> trash row 49, weights exactly 0); row reduce
// via ones-B-fragment MFMA; A2 in bf16 aliasing dead q/k staging; output
// unnormalized bf16 + f32 rowsum, normalization folded into proj staging.
// ---------------------------------------------------------------------------
__global__ __launch_bounds__(256, 4) void dwa_attn(
    const short* __restrict__ qkv_bf, const __half* __restrict__ off_h,
    const float* __restrict__ rpb, short* __restrict__ attn_bf,
    float* __restrict__ rs_buf) {
  __shared__ __align__(16) short scr_all[4 * 3200];  // per-wave [50][64] bf16
  __shared__ __align__(16) short region1[3840];   // qbs(1280)+kbs(2560) / A2b
  __shared__ __align__(16) __half S0h[1356];      // [26][52] fp16 + pad
  __shared__ __align__(16) short vbT[32 * 72];    // bf16 v^T [d][m]

  short* qbs = region1;          // [32][40] bf16
  short* kbs = region1 + 1280;   // [64][40] bf16
  short* A2b = region1;          // [32][72] bf16 (aliases qbs/kbs after P2)

  const int bid = blockIdx.x;
  const int swz = (bid & 7) * 256 + (bid >> 3);
  const int b = swz >> 3;
  const int sub = swz & 7;
  const int h = sub >> 1;
  const int half = sub & 1;
  const int bn0 = half * 25;
  const int rcnt = half ? 24 : 25;

  const int tid = threadIdx.x;
  const int lane = tid & 63;
  const int wv = tid >> 6;
  const int lr = lane & 15;
  const int lg = lane >> 4;
  short* scr = scr_all + wv * 3200;  // this wave's [50][64] bf16 scratch

  // per-lane k2 constants (lane = k2)
  const int kk2 = (lane < 49) ? lane : 48;
  const int ky = kk2 / 7;
  const int kx = kk2 - ky * 7;
  const float bias_r = rpb[h * 169 + (ky + 3) * 13 + (kx + 3)];

  // ---- prefetch offsets for my wave's rows (<=7) ----
  const __half* offp = off_h + (size_t)(b * 49) * 392 + h * 98;
  float2 offr[7];
#pragma unroll
  for (int i = 0; i < 7; ++i) {
    int nl = wv + 4 * i;
    if (nl < rcnt && lane < 49) {
      __half2 o2 =
          *(const __half2*)(offp + (size_t)(bn0 + nl) * 392 + lane * 2);
      offr[i] = __half22float2(o2);
    } else {
      offr[i] = make_float2(0.f, 0.f);
    }
  }

  // ---- P1 stage (pure copies) + full scr zero (once) ----
  {
    short8 zz = {0, 0, 0, 0, 0, 0, 0, 0};
    {
      int r = tid >> 2, c4 = tid & 3;
      short8 pk = zz;
      if (r < 49)
        pk = *(const short8*)(qkv_bf + (size_t)(b * 49 + r) * 384 + 128 +
                              h * 32 + c4 * 8);
      *(short8*)&kbs[r * 40 + c4 * 8] = pk;
    }
    if (tid < 128) {
      int r = tid >> 2, c4 = tid & 3;
      short8 pk = zz;
      if (r < rcnt)
        pk = *(const short8*)(qkv_bf + (size_t)(b * 49 + bn0 + r) * 384 +
                              h * 32 + c4 * 8);
      *(short8*)&qbs[r * 40 + c4 * 8] = pk;
    }
    const short* vbase = qkv_bf + (size_t)(b * 49) * 384 + 256 + h * 32;
#pragma unroll
    for (int it = 0; it < 7; ++it) {
      int i = tid + it * 256;
      if (i < 1568) {
        int n = i >> 5;
        int d = i & 31;
        vbT[d * 72 + n] = vbase[(size_t)n * 384 + d];
      }
    }
    for (int i = tid; i < 480; i += 256) {  // zero vbT cols 49..63, all d
      int d = i / 15;
      int j = i - d * 15;
      vbT[d * 72 + 49 + j] = 0;
    }
    if (tid < 16) S0h[25 * 52 + tid] = __float2half(0.f);
    // zero this wave's FULL scr (50 rows x 64 = 400 chunks of 8)
    for (int c = lane; c < 400; c += 64) *(short8*)&scr[c * 8] = zz;
  }
  __syncthreads();  // B1

  // ---- P2: S0h[n][m] = k_m . q_n via mfma(A=k, B=q); fp16 b64 writes ----
  {
    const int mt = wv;
    short8 af = *(const short8*)&kbs[(mt * 16 + lr) * 40 + lg * 8];
    floatx4 z = {0.f, 0.f, 0.f, 0.f};
#pragma unroll
    for (int nt = 0; nt < 2; ++nt) {
      short8 bf = *(const short8*)&qbs[(nt * 16 + lr) * 40 + lg * 8];
      floatx4 c = __builtin_amdgcn_mfma_f32_16x16x32_bf16(af, bf, z, 0, 0, 0);
      int n = nt * 16 + lr;
      int mbase = mt * 16 + lg * 4;
      if (n < 26 && mbase < 52) {  // both guards required (row pitch 52)
        short4 pk;
        pk.x = (short)__half_as_ushort(__float2half(c[0]));
        pk.y = (short)__half_as_ushort(__float2half(c[1]));
        pk.z = (short)__half_as_ushort(__float2half(c[2]));
        pk.w = (short)__half_as_ushort(__float2half(c[3]));
        *(short4*)&S0h[n * 52 + mbase] = pk;
      }
    }
  }
  __syncthreads();  // B2 (q/k region dead; A2b region writable per-wave)

  // ---- P3: per-wave row loop -- scores + plain scatter + MFMA reduce ----
  {
    short8 bones;
#pragma unroll
    for (int u = 0; u < 8; ++u) bones[u] = (lr == 0) ? (short)0x3F80 : (short)0;
    const int lchunk = lane >> 3;   // scatter column chunk
    const int lsub = lane & 7;

#pragma unroll
    for (int i = 0; i < 7; ++i) {
      const int nl = wv + 4 * i;
      if (nl >= rcnt) break;
      int so0 = 0, so1 = 0, so2 = 0, so3 = 0;
      // scatter: plain bf16 stores, per-lane distinct cells (scr pre-zeroed)
      if (lane < 49) {
        const int gn = bn0 + nl;
        const int iy = (int)((unsigned)gn / 7u);
        const int ix = gn - iy * 7;
        float py = fminf(fmaxf((float)(iy + ky - 3) + offr[i].x, 0.f), 6.f);
        float px = fminf(fmaxf((float)(ix + kx - 3) + offr[i].y, 0.f), 6.f);
        float y0f = floorf(py), x0f = floorf(px);
        float wy = py - y0f, wx = px - x0f;
        int y0 = (int)y0f, x0 = (int)x0f;
        int c00 = y0 * 7 + x0;
        int sbase = nl * 52 + c00;
        float s00 = __half2float(S0h[sbase]);
        float s01 = __half2float(S0h[sbase + 1]);
        float s10 = __half2float(S0h[sbase + 7]);
        float s11 = __half2float(S0h[sbase + 8]);
        float w00 = (1.f - wy) * (1.f - wx);
        float w01 = (1.f - wy) * wx;
        float w10 = wy * (1.f - wx);
        float w11 = wy * wx;
        float s = w00 * s00 + w01 * s01 + w10 * s10 + w11 * s11 + bias_r;
        float pe = __expf(s);
        // duplicate cells (weight==0 exactly) -> single trash row 49
        bool xc = (x0 == 6), yc = (y0 == 6);
        int c01 = xc ? 49 : c00 + 1;
        int c10 = yc ? 49 : c00 + 7;
        int c11 = (xc || yc) ? 49 : c00 + 8;
        so0 = c00 * 64 + ((lchunk ^ (c00 & 7)) * 8) + lsub;
        so1 = c01 * 64 + ((lchunk ^ (c01 & 7)) * 8) + lsub;
        so2 = c10 * 64 + ((lchunk ^ (c10 & 7)) * 8) + lsub;
        so3 = c11 * 64 + ((lchunk ^ (c11 & 7)) * 8) + lsub;
        scr[so0] = f2bf(pe * w00);
        scr[so1] = f2bf(pe * w01);
        scr[so2] = f2bf(pe * w10);
        scr[so3] = f2bf(pe * w11);
      }
      // (no fences: in-order DS pipe + may-alias ordering guarantee the
      //  reduce reads observe this wave's scatter stores)
      // reduce: A2row[m] = sum over 64 cols via ones-B MFMA
      __builtin_amdgcn_s_setprio(1);
#pragma unroll
      for (int tile = 0; tile < 4; ++tile) {
        floatx4 cacc = {0.f, 0.f, 0.f, 0.f};
#pragma unroll
        for (int ks = 0; ks < 2; ++ks) {
          int row = tile * 16 + lr;
          int chunk = ks * 4 + lg;
          short8 af =
              *(const short8*)&scr[row * 64 + ((chunk ^ (row & 7)) * 8)];
          cacc = __builtin_amdgcn_mfma_f32_16x16x32_bf16(af, bones, cacc,
                                                         0, 0, 0);
        }
        if ((lane & 15) == 0) {
          int mb = tile * 16 + (lane >> 4) * 4;
#pragma unroll
          for (int reg = 0; reg < 4; ++reg) {
            int m = mb + reg;
            A2b[nl * 72 + m] = (m <= 48) ? f2bf(cacc[reg]) : (short)0;
          }
        }
      }
      __builtin_amdgcn_s_setprio(0);
      // re-zero own 4 slots (ordered after reduce reads by may-alias rule)
      if (lane < 49) {
        scr[so0] = 0;
        scr[so1] = 0;
        scr[so2] = 0;
        scr[so3] = 0;
      }
    }
  }
  __syncthreads();  // B3

  // ---- P5: out (bf16, unnormalized) + rowsum via MFMA ----
  {
    const int nt = wv & 1;
    const int dt = wv >> 1;
    floatx4 acc = {0.f, 0.f, 0.f, 0.f};
    floatx4 accS = {0.f, 0.f, 0.f, 0.f};
    short8 bones;
#pragma unroll
    for (int u = 0; u < 8; ++u) bones[u] = (lr == 0) ? (short)0x3F80 : (short)0;
#pragma unroll
    for (int ks = 0; ks < 2; ++ks) {
      short8 af = *(const short8*)&A2b[(nt * 16 + lr) * 72 + ks * 32 + lg * 8];
      short8 bf = *(const short8*)&vbT[(dt * 16 + lr) * 72 + ks * 32 + lg * 8];
      acc = __builtin_amdgcn_mfma_f32_16x16x32_bf16(af, bf, acc, 0, 0, 0);
      if (dt == 0)
        accS = __builtin_amdgcn_mfma_f32_16x16x32_bf16(af, bones, accS, 0, 0, 0);
    }
    const int d = dt * 16 + lr;
#pragma unroll
    for (int reg = 0; reg < 4; ++reg) {
      int n = nt * 16 + lg * 4 + reg;
      if (n < rcnt) {
        int grow = b * 49 + bn0 + n;
        attn_bf[(size_t)grow * 128 + h * 32 + d] = f2bf(acc[reg]);
        if (dt == 0 && lr == 0) rs_buf[(size_t)grow * 4 + h] = accS[reg];
      }
    }
  }
}

// ---------------------------------------------------------------------------
// Proj GEMM: out = diag(1/rs per head) * attn_bf @ w_proj^T + b_proj
// ---------------------------------------------------------------------------
__global__ __launch_bounds__(256) void dwa_proj(
    const short* __restrict__ A, const float* __restrict__ W0,
    const float* __restrict__ bias0, float* __restrict__ out0,
    const float* __restrict__ rs) {
  __shared__ short Abs[64][128];
  __shared__ short Bbs[64][128];
  const int tid = threadIdx.x;
  const int m0 = blockIdx.x * 64;
  const int n0 = blockIdx.y * 64;

#pragma unroll
  for (int p = 0; p < 4; ++p) {
    int c = tid + p * 256;
    int row = c >> 4;
    int slot = c & 15;
    short8 v = *(const short8*)(A + (size_t)(m0 + row) * 128 + slot * 8);
    float irs = 1.0f / rs[(size_t)(m0 + row) * 4 + (slot >> 2)];
    short8 pk;
#pragma unroll
    for (int u = 0; u < 8; ++u) pk[u] = f2bf(bf2f(v[u]) * irs);
    *(short8*)&Abs[row][(slot ^ (row & 7)) * 8] = pk;
  }
#pragma unroll
  for (int p = 0; p < 4; ++p) {
    int c = tid + p * 256;
    int row = c >> 4;
    int slot = c & 15;
    const float* src = W0 + (size_t)(n0 + row) * 128 + slot * 8;
    float4 f0 = *(const float4*)(src);
    float4 f1 = *(const float4*)(src + 4);
    short8 pk;
    pk[0] = f2bf(f0.x); pk[1] = f2bf(f0.y); pk[2] = f2bf(f0.z); pk[3] = f2bf(f0.w);
    pk[4] = f2bf(f1.x); pk[5] = f2bf(f1.y); pk[6] = f2bf(f1.z); pk[7] = f2bf(f1.w);
    *(short8*)&Bbs[row][(slot ^ (row & 7)) * 8] = pk;
  }
  __syncthreads();

  const int lane = tid & 63;
  const int wv = tid >> 6;
  const int wrow = (wv >> 1) * 32;
  const int wcol = (wv & 1) * 32;
  const int lr = lane & 15;
  const int lg = lane >> 4;

  floatx4 acc[2][2];
#pragma unroll
  for (int i = 0; i < 2; ++i)
#pragma unroll
    for (int j = 0; j < 2; ++j) acc[i][j] = {0.f, 0.f, 0.f, 0.f};

#pragma unroll
  for (int ks = 0; ks < 4; ++ks) {
    short8 af[2], bf[2];
#pragma unroll
    for (int i = 0; i < 2; ++i) {
      int r = wrow + i * 16 + lr;
      int slot = (ks * 4 + lg) ^ (r & 7);
      af[i] = *(const short8*)&Abs[r][slot * 8];
    }
#pragma unroll
    for (int j = 0; j < 2; ++j) {
      int r = wcol + j * 16 + lr;
      int slot = (ks * 4 + lg) ^ (r & 7);
      bf[j] = *(const short8*)&Bbs[r][slot * 8];
    }
#pragma unroll
    for (int i = 0; i < 2; ++i)
#pragma unroll
      for (int j = 0; j < 2; ++j)
        acc[i][j] = __builtin_amdgcn_mfma_f32_16x16x32_bf16(af[i], bf[j],
                                                            acc[i][j], 0, 0, 0);
  }

#pragma unroll
  for (int i = 0; i < 2; ++i) {
#pragma unroll
    for (int reg = 0; reg < 4; ++reg) {
      int grow = m0 + wrow + i * 16 + lg * 4 + reg;
#pragma unroll
      for (int j = 0; j < 2; ++j) {
        int gcol = n0 + wcol + j * 16 + lr;
        out0[(size_t)grow * 128 + gcol] = acc[i][j][reg] + bias0[gcol];
      }
    }
  }
}

// ---------------------------------------------------------------------------
extern "C" void kernel_launch(void* const* d_in, const int* in_sizes, int n_in,
                              void* d_out, int out_size, void* d_ws,
                              size_t ws_size, hipStream_t stream) {
  const float* x = (const float*)d_in[0];
  const float* w_qkv = (const float*)d_in[1];
  const float* b_qkv = (const float*)d_in[2];
  const float* w_off = (const float*)d_in[3];
  const float* b_off = (const float*)d_in[4];
  const float* rpb = (const float*)d_in[5];
  const float* w_proj = (const float*)d_in[6];
  const float* b_proj = (const float*)d_in[7];
  float* out = (float*)d_out;

  char* ws = (char*)d_ws;
  short* qkv_bf = (short*)ws;                               // 9,633,792 B
  __half* off_h = (__half*)(ws + 9633792);                  // 9,834,496 B
  short* attn_bf = (short*)(ws + 19468288);                 // 3,211,264 B
  float* rs_buf = (float*)(ws + 22679552);                  // 200,704 B

  dwa_gemm0<<<dim3(196, 5), 256, 0, stream>>>(x, w_qkv, w_off, b_qkv, b_off,
                                              qkv_bf, off_h);
  dwa_attn<<<2048, 256, 0, stream>>>(qkv_bf, off_h, rpb, attn_bf, rs_buf);
  dwa_proj<<<dim3(196, 2), 256, 0, stream>>>(attn_bf, w_proj, b_proj, out,
                                             rs_buf);
}